// Round 14
// baseline (131.556 us; speedup 1.0000x reference)
//
#include <hip/hip_runtime.h>

#define BATCH 16
#define IMG 96
#define NWIN 9
#define M_FILT 16
#define SP 22
#define FIN (M_FILT * SP * SP)   // 7744
#define NPP (SP * SP)            // 484

typedef float f32x2 __attribute__((ext_vector_type(2)));
typedef float f32x4 __attribute__((ext_vector_type(4)));
typedef _Float16 h2 __attribute__((ext_vector_type(2)));

// Packed-f16 t(z) = 1.1 + atan(z)/pi, branch-free double-angle (R12-proven
// formulation, halved issue slots via v_pk_*_f16):
//   u = z/(1+sqrt(1+z^2)), atan(z) = 2*atan(u), t = 1.1 + u*P(u^2).
// f16 trans (sqrt/rcp per half) overlap the VALU stream.
__device__ __forceinline__ h2 dend_h2(h2 z) {
    const h2 ONE = {(_Float16)1.0f, (_Float16)1.0f};
    const h2 HMX = {(_Float16)49152.0f, (_Float16)49152.0f};  // overflow guard
    const h2 CK0 = {(_Float16)0.6334047f, (_Float16)0.6334047f};
    const h2 CK1 = {(_Float16)-0.1827287f, (_Float16)-0.1827287f};
    const h2 CK2 = {(_Float16)0.0496796f, (_Float16)0.0496796f};
    const h2 C11 = {(_Float16)1.1f, (_Float16)1.1f};
    h2 h = __builtin_elementwise_fma(z, z, ONE);          // 1 + z^2
    h = __builtin_elementwise_min(h, HMX);
    h2 sq;
    sq.x = __builtin_amdgcn_sqrth(h.x);                   // v_sqrt_f16
    sq.y = __builtin_amdgcn_sqrth(h.y);
    h2 d = sq + ONE;
    h2 rr;
    rr.x = __builtin_amdgcn_rcph(d.x);                    // v_rcp_f16
    rr.y = __builtin_amdgcn_rcph(d.y);
    h2 u = z * rr;
    h2 s = u * u;
    h2 p = __builtin_elementwise_fma(s, CK2, CK1);
    p = __builtin_elementwise_fma(s, p, CK0);
    return __builtin_elementwise_fma(u, p, C11);
}

struct WQ { h2 w2; h2 q2; };   // {10w,10w},{-10q,-10q} — 8 B, one ds_read_b64

// ---------------------------------------------------------------------------
// Kernel 1: dendrite + 4x4 maxpool, packed-f16 evals.
// Block = one (b, m, pp-chunk): threads = [ di(2b) | pp_local(6b) ].
// Per row: 12 x-floats -> 11 overlapping f16 pairs; per tap: 2 pk_fma (z for
// windows {0,1} and {2,3}) + 2 packed dend evals; row-products kept in f16
// (range [0.01,69]) and folded into f32 window products each row.
// Single log2 after the dj/di max reduction.
// ---------------------------------------------------------------------------
__global__ __launch_bounds__(256, 8) void dendrite_pool_kernel(
    const float* __restrict__ x,      // [B,96,96]
    const float* __restrict__ w,      // [16,9,9]
    const float* __restrict__ q,      // [16,9,9]
    float* __restrict__ pooled,       // [B, FIN]
    const float* __restrict__ fc2b,   // [10]
    float* __restrict__ out)          // [B, 10]
{
    const int tid   = threadIdx.x;
    const int chunk = blockIdx.x & 7;
    const int m     = (blockIdx.x >> 3) & 15;   // block-uniform
    const int b     = blockIdx.x >> 7;          // block-uniform

    if (blockIdx.x == 0 && tid < BATCH * 10) {
        out[tid] = fc2b[tid % 10];              // out = b2 (fc kernel adds on top)
    }

    __shared__ WQ swq[NWIN * NWIN];
    if (tid < NWIN * NWIN) {
        float wv = 10.0f * w[m * 81 + tid];
        float qv = -10.0f * q[m * 81 + tid];
        _Float16 wh = (_Float16)wv, qh = (_Float16)qv;
        WQ t; t.w2 = (h2){wh, wh}; t.q2 = (h2){qh, qh};
        swq[tid] = t;
    }
    __syncthreads();

    const int di  = tid & 3;
    const int ppl = tid >> 2;                   // 0..63
    const int pp  = chunk * 64 + ppl;
    const int ppc = pp < NPP ? pp : (NPP - 1);  // clamp to stay in-bounds
    const int pj  = ppc % SP;
    const int pi  = ppc / SP;

    const float* xb = x + b * IMG * IMG + (pi * 4 + di) * IMG + pj * 4;

    float p0 = 1.f, p1 = 1.f, p2 = 1.f, p3 = 1.f;   // f32 window products

    #pragma unroll 1
    for (int r = 0; r < NWIN; ++r) {
        const f32x4* xr = reinterpret_cast<const f32x4*>(xb + r * IMG);
        f32x4 X0 = xr[0], X1 = xr[1], X2 = xr[2];
        float xs[12] = {X0.x, X0.y, X0.z, X0.w,
                        X1.x, X1.y, X1.z, X1.w,
                        X2.x, X2.y, X2.z, X2.w};
        h2 xp[11];
        #pragma unroll
        for (int c = 0; c < 11; ++c) {
            xp[c] = (h2){(_Float16)xs[c], (_Float16)xs[c + 1]};
        }

        h2 rowA = {(_Float16)1.0f, (_Float16)1.0f};   // windows dj=0,1
        h2 rowB = {(_Float16)1.0f, (_Float16)1.0f};   // windows dj=2,3

        #pragma unroll
        for (int c = 0; c < 9; ++c) {
            WQ wq = swq[r * 9 + c];                   // uniform ds_read_b64
            h2 zA = __builtin_elementwise_fma(xp[c],     wq.w2, wq.q2);
            h2 zB = __builtin_elementwise_fma(xp[c + 2], wq.w2, wq.q2);
            rowA = rowA * dend_h2(zA);
            rowB = rowB * dend_h2(zB);
        }

        p0 *= (float)rowA.x;
        p1 *= (float)rowA.y;
        p2 *= (float)rowB.x;
        p3 *= (float)rowB.y;
    }

    float best = fmaxf(fmaxf(p0, p1), fmaxf(p2, p3));
    best = fmaxf(best, __shfl_xor(best, 1, 64));   // di reduction
    best = fmaxf(best, __shfl_xor(best, 2, 64));
    if (di == 0 && pp < NPP) {
        pooled[b * FIN + pp * 16 + m] = __builtin_amdgcn_logf(best) * 0.69314718056f;
    }
}

// ---------------------------------------------------------------------------
// Kernel 2: fused FC1 (7744->128, bias+ReLU) + FC2 (128->10) scatter.
// One block per output neuron o (512 threads); weight row read once; batch
// dots in registers; final scatter via atomics (out pre-set to b2).
// ---------------------------------------------------------------------------
__global__ __launch_bounds__(512) void fc_fused_kernel(
    const float* __restrict__ pooled,  // [B, FIN]
    const float* __restrict__ w1,      // [128, FIN]
    const float* __restrict__ b1,      // [128]
    const float* __restrict__ w2,      // [10, 128]
    float* __restrict__ out)           // [B, 10]
{
    int o = blockIdx.x;
    const float* wr = w1 + o * FIN;

    float acc[BATCH];
    #pragma unroll
    for (int b = 0; b < BATCH; ++b) acc[b] = 0.f;

    for (int f = threadIdx.x; f < FIN; f += 512) {
        float wv = wr[f];
        #pragma unroll
        for (int b = 0; b < BATCH; ++b)
            acc[b] = fmaf(pooled[b * FIN + f], wv, acc[b]);
    }

    #pragma unroll
    for (int b = 0; b < BATCH; ++b) {
        #pragma unroll
        for (int off = 32; off > 0; off >>= 1)
            acc[b] += __shfl_down(acc[b], off, 64);
    }

    __shared__ float red[8][BATCH];
    __shared__ float hrow[BATCH];
    int wid = threadIdx.x >> 6, lane = threadIdx.x & 63;
    if (lane == 0) {
        #pragma unroll
        for (int b = 0; b < BATCH; ++b) red[wid][b] = acc[b];
    }
    __syncthreads();
    if (threadIdx.x < BATCH) {
        int b = threadIdx.x;
        float s_ = b1[o];
        #pragma unroll
        for (int k = 0; k < 8; ++k) s_ += red[k][b];
        hrow[b] = fmaxf(s_, 0.f);
    }
    __syncthreads();
    if (threadIdx.x < BATCH * 10) {
        int b = threadIdx.x / 10, c = threadIdx.x % 10;
        atomicAdd(&out[b * 10 + c], hrow[b] * w2[c * 128 + o]);
    }
}

// ---------------------------------------------------------------------------
extern "C" void kernel_launch(void* const* d_in, const int* in_sizes, int n_in,
                              void* d_out, int out_size, void* d_ws, size_t ws_size,
                              hipStream_t stream)
{
    const float* x    = (const float*)d_in[0];
    const float* w    = (const float*)d_in[1];
    const float* q    = (const float*)d_in[2];
    const float* fc1w = (const float*)d_in[3];
    const float* fc1b = (const float*)d_in[4];
    const float* fc2w = (const float*)d_in[5];
    const float* fc2b = (const float*)d_in[6];
    float* out = (float*)d_out;

    float* pooled = (float*)d_ws;                 // B*FIN floats

    // grid: [ b(4b) | m(4b) | chunk(3b) ] = 2048 blocks
    dendrite_pool_kernel<<<2048, 256, 0, stream>>>(x, w, q, pooled, fc2b, out);
    fc_fused_kernel<<<128, 512, 0, stream>>>(pooled, fc1w, fc1b, fc2w, out);
}